// Round 17
// baseline (46.124 us; speedup 1.0000x reference)
//
#include <hip/hip_runtime.h>
#include <cmath>

#define THREADS 256
#define NCELL 10
#define DDIM 9

#define LN2F 0.69314718056f
#define RLN2F 1.4426950408889634f  /* 1/ln2 */
#define K10L 14.426950408889634f   /* 10/ln2 */
#define LIN_THR_L 1.442695e-10f    /* 1e-10/ln2 */

typedef float f32x2 __attribute__((ext_vector_type(2)));
typedef float f32x4 __attribute__((ext_vector_type(4)));

__device__ __forceinline__ f32x2 fma2(f32x2 a, f32x2 b, f32x2 c) {
  return __builtin_elementwise_fma(a, b, c);   // v_pk_fma_f32 on gfx950
}
__device__ __forceinline__ f32x2 max2(f32x2 a, f32x2 b) {
  return __builtin_elementwise_max(a, b);      // v_pk_max_f32
}

struct Basis { float Bt[DDIM][2 * NCELL]; }; // Bt[t][l] = B[l][t]

// Reproduce numpy.linalg.svd(L) Vt[11:] rows: LAPACK dgesdd Path 4t leaves
// rows m..n-1 of VT equal to the LQ-factorization orthogonal complement.
static void compute_basis_host(Basis* bs) {
  double L[11][20];
  for (int r = 0; r < 11; ++r)
    for (int c = 0; c < 20; ++c) L[r][c] = 0.0;
  for (int k = 1; k < NCELL; ++k) {
    double xk = (double)k / (double)NCELL;
    L[k - 1][2 * (k - 1)] = xk;
    L[k - 1][2 * (k - 1) + 1] = 1.0;
    L[k - 1][2 * k] = -xk;
    L[k - 1][2 * k + 1] = -1.0;
  }
  L[NCELL - 1][1] = 1.0;
  L[NCELL][2 * (NCELL - 1)] = 1.0;
  L[NCELL][2 * (NCELL - 1) + 1] = 1.0;

  double v[11][20];
  double tau[11];
  for (int i = 0; i < 11; ++i) {
    double alpha = L[i][i];
    double xn2 = 0.0;
    for (int l = i + 1; l < 20; ++l) xn2 += L[i][l] * L[i][l];
    double xnorm = sqrt(xn2);
    for (int l = 0; l < 20; ++l) v[i][l] = 0.0;
    v[i][i] = 1.0;
    if (xnorm == 0.0) {
      tau[i] = 0.0;
    } else {
      double beta = sqrt(alpha * alpha + xn2);
      if (alpha >= 0.0) beta = -beta;        // dlarfg: beta = -sign(alpha)*norm
      tau[i] = (beta - alpha) / beta;
      double sc = 1.0 / (alpha - beta);
      for (int l = i + 1; l < 20; ++l) v[i][l] = L[i][l] * sc;
      L[i][i] = beta;
      for (int j = i + 1; j < 11; ++j) {
        double w = 0.0;
        for (int l = i; l < 20; ++l) w += L[j][l] * v[i][l];
        w *= tau[i];
        for (int l = i; l < 20; ++l) L[j][l] -= w * v[i][l];
      }
    }
  }
  for (int j = 11; j < 20; ++j) {
    double q[20];
    for (int l = 0; l < 20; ++l) q[l] = 0.0;
    q[j] = 1.0;
    for (int i = 10; i >= 0; --i) {
      double w = 0.0;
      for (int l = i; l < 20; ++l) w += v[i][l] * q[l];
      w *= tau[i];
      for (int l = i; l < 20; ++l) q[l] -= w * v[i][l];
    }
    for (int l = 0; l < 20; ++l) bs->Bt[j - 11][l] = (float)q[l];
  }
}

// Per-MLP folds (130 floats each; m1 at ws[0], m2 at ws[130]):
//  [0:10)    W01[j]  = sum_r w0[r]*w1[r,j]       (layer0+1 fold: NO ReLU between)
//  [10:20)   B01[j]  = sum_r b0[r]*w1[r,j] + b1[j]
//  [20:120)  W3V[r][k] = sum_t w3[r,t]*VB[t][k+1], k=0..8; k=9 -> 0 (v10 pad)
//  [120:130) B3V[k]  = sum_t b3[t]*VB[t][k+1],  k=0..8; k=9 -> 0
__global__ void fold_kernel(
    const float* __restrict__ w0_1, const float* __restrict__ b0_1,
    const float* __restrict__ w1_1, const float* __restrict__ b1_1,
    const float* __restrict__ w3_1, const float* __restrict__ b3_1,
    const float* __restrict__ w0_2, const float* __restrict__ b0_2,
    const float* __restrict__ w1_2, const float* __restrict__ b1_2,
    const float* __restrict__ w3_2, const float* __restrict__ b3_2,
    float* __restrict__ ws, Basis bb) {
  for (int f = threadIdx.x; f < 260; f += THREADS) {
    int m = f / 130;
    int j = f % 130;
    const float* w0 = (m == 0) ? w0_1 : w0_2;
    const float* b0 = (m == 0) ? b0_1 : b0_2;
    const float* w1 = (m == 0) ? w1_1 : w1_2;
    const float* w3 = (m == 0) ? w3_1 : w3_2;
    const float* b3 = (m == 0) ? b3_1 : b3_2;
    const float* b1 = (m == 0) ? b1_1 : b1_2;
    float val = 0.0f;
    if (j < 10) {
      for (int r = 0; r < 10; ++r) val += w0[r] * w1[r * 10 + j];
    } else if (j < 20) {
      int jj = j - 10;
      for (int r = 0; r < 10; ++r) val += b0[r] * w1[r * 10 + jj];
      val += b1[jj];
    } else if (j < 120) {
      int jj = j - 20;
      int r = jj / 10, k = jj % 10;
      if (k < 9) {
        float g = (float)(k + 1) * 0.1f;
        for (int t = 0; t < DDIM; ++t)
          val += w3[r * DDIM + t] * (bb.Bt[t][2 * (k + 1)] * g + bb.Bt[t][2 * (k + 1) + 1]);
      }
    } else {
      int k = j - 120;
      if (k < 9) {
        float g = (float)(k + 1) * 0.1f;
        for (int t = 0; t < DDIM; ++t)
          val += b3[t] * (bb.Bt[t][2 * (k + 1)] * g + bb.Bt[t][2 * (k + 1) + 1]);
      }
    }
    ws[f] = val;
  }
}

// Folded MLP: h1 = relu(x*W01+B01); h2 = relu(h1@w2+b2); v1..v9 = h2@W3V+B3V
// (v0 = v10 = 0). Derive per cell: a_c = 10*(v[c+1]-v[c]),
// b_c = v[c] - a_c*(c/10) — identical to theta@B^T in exact arithmetic.
// Writes (a,b) to this thread's LDS column; returns min|a| for the lin vote.
__device__ __forceinline__ void mlp_A(float xin,
    const float* __restrict__ w2, const float* __restrict__ b2,
    const float* __restrict__ wbf,     // 130 floats (layout above)
    f32x2* abcol, float& amin) {
  const f32x2* W01 = (const f32x2*)wbf;         // [0:5)
  const f32x2* B01 = W01 + 5;                   // [5:10)
  const f32x2* W3V = W01 + 10;                  // [10:60): 10 rows x 5 pairs
  const f32x2* B3V = W01 + 60;                  // [60:65)
  const f32x2* w2p = (const f32x2*)w2;
  const f32x2* b2p = (const f32x2*)b2;

  f32x2 h1[5], h2[5];
  f32x2 xx = {xin, xin};
  f32x2 zero = {0.0f, 0.0f};
#pragma unroll
  for (int p = 0; p < 5; ++p) h1[p] = max2(fma2(xx, W01[p], B01[p]), zero);

#pragma unroll
  for (int p = 0; p < 5; ++p) h2[p] = b2p[p];
#pragma unroll
  for (int r = 0; r < 10; ++r) {
    float h = h1[r >> 1][r & 1];
    f32x2 hh = {h, h};
#pragma unroll
    for (int p = 0; p < 5; ++p) h2[p] = fma2(hh, w2p[r * 5 + p], h2[p]);
  }
#pragma unroll
  for (int p = 0; p < 5; ++p) h2[p] = max2(h2[p], zero);

  f32x2 vp[5];                                   // (v1,v2)..(v9,v10=0)
#pragma unroll
  for (int p = 0; p < 5; ++p) vp[p] = B3V[p];
#pragma unroll
  for (int r = 0; r < 10; ++r) {
    float h = h2[r >> 1][r & 1];
    f32x2 hh = {h, h};
#pragma unroll
    for (int p = 0; p < 5; ++p) vp[p] = fma2(hh, W3V[r * 5 + p], vp[p]);
  }

  float v[NCELL + 1];
  v[0] = 0.0f;
#pragma unroll
  for (int k = 1; k <= NCELL; ++k) v[k] = vp[(k - 1) >> 1][(k - 1) & 1];

  float mn = 1e30f;
#pragma unroll
  for (int c = 0; c < NCELL; ++c) {
    float ac = (v[c + 1] - v[c]) * 10.0f;
    float bc = fmaf(ac, -(float)c * 0.1f, v[c]);
    f32x2 ab; ab[0] = ac; ab[1] = bc;
    abcol[c * THREADS] = ab;
    mn = fminf(mn, fabsf(ac));
  }
  amin = mn;
}

// Freeze-form cell-hop loop (best-measured r13 structure):
//  - v continuous across cells -> v_entry := vxc_prev register-exact; no
//    per-iter v=fma(a,phi,b).
//  - monotone direction -> dir/d01 hoisted; xc += d01; c += dirI.
//  - terminal lanes are fixed points of the update (cross=false sticks);
//    no active/trem bookkeeping. Exit vote __all(!cross).
//  - exp/evolve deferred post-loop; ld telescoped to terminal ENTRY:
//    ld = log(vterm/v0) + aF*t with the evolve factor added in LOG SPACE
//    (exact) — never recompute v(z) (r12 cancellation lesson).
//  - guards: ratio clamp 1e-30, |v|<1e-14 tiny -> no-cross, lin fixup
//    behind wave-uniform __any(lin) vote (hoisted from mlp_A's min|a|).
__device__ __forceinline__ void flow_dev(float x0, const f32x2* abcol,
                                         bool has_lin, float& zo, float& ldo) {
  int c = (int)(x0 * 10.0f);
  c = c < 0 ? 0 : (c > 9 ? 9 : c);
  f32x2 ab = abcol[c * THREADS];
  float a = ab[0], b = ab[1];
  float v0 = fmaf(a, x0, b);
  bool right = (v0 >= 0.0f);
  float d01 = right ? 0.1f : -0.1f;
  int dirI = right ? 1 : -1;
  float xc = (float)(right ? (c + 1) : c) * 0.1f;
  float rv0 = __builtin_amdgcn_rcpf(v0);
  float rv = rv0;
  bool tiny = fabsf(v0) < 1e-14f;
  float ra = __builtin_amdgcn_rcpf(a);
  float phiC = x0;           // entry point of current cell
  float t = 1.0f;            // remaining time; freezes at terminal
  bool cross = false;

  // prefetch next cell in travel direction
  int cn = c + dirI; cn = cn < 0 ? 0 : (cn > 9 ? 9 : cn);
  f32x2 abn = abcol[cn * THREADS];
  float ran = __builtin_amdgcn_rcpf(abn[0]);

  for (int it = 0; it < NCELL; ++it) {
    float vxc = fmaf(a, xc, b);
    float ratio = fmaxf(vxc * rv, 1e-30f);
    float l = __logf(ratio);                       // v_log_f32
    float thit = l * ra;
    if (has_lin) {                                 // hoisted; ~never taken
      bool lin = fabsf(a) < 1e-10f;
      float sb = (fabsf(b) < 1e-30f) ? 1.0f : b;
      float tl = (xc - phiC) * __builtin_amdgcn_rcpf(sb);
      thit = lin ? tl : thit;
    }
    cross = (thit < t) && !tiny;
    t = cross ? (t - thit) : t;
    phiC = cross ? xc : phiC;
    float rvn = __builtin_amdgcn_rcpf(vxc);        // off-chain
    rv = cross ? rvn : rv;
    tiny = cross ? (fabsf(vxc) < 1e-14f) : tiny;
    a = cross ? abn[0] : a;
    b = cross ? abn[1] : b;
    ra = cross ? ran : ra;
    xc = cross ? (xc + d01) : xc;
    c = cross ? cn : c;
    if (__all(!cross)) break;
    int cnn = c + dirI; cnn = cnn < 0 ? 0 : (cnn > 9 ? 9 : cnn);
    abn = abcol[cnn * THREADS];                    // prefetch for next iter
    ran = __builtin_amdgcn_rcpf(abn[0]);
    cn = cnn;
  }
  // post-loop: telescoped ld (v_term/v0) + one evolve inside the terminal
  // cell (reference formulas); (a,b)/phiC/t all live in registers.
  bool done = !cross;        // false only if still crossing at exhaustion
  float vterm = fmaf(a, phiC, b);
  float ld = __logf(fmaxf(vterm * rv0, 1e-30f));   // == sum of crossed log-ratios
  bool linf = fabsf(a) < 1e-10f;
  float rsaf = __builtin_amdgcn_rcpf(linf ? 1.0f : a);
  float bsa = b * rsaf;
  float E = __expf(a * t);                         // the ONLY exp in the flow
  float pnl = fmaf(phiC + bsa, E, -bsa);
  float pli = fmaf(b, t, phiC);
  float p1 = linf ? pli : pnl;
  zo = done ? p1 : phiC;
  ldo = ld + (done ? a * t : 0.0f);
}

__global__ __launch_bounds__(THREADS, 4) void cpab2d_kernel(
    const float* __restrict__ x,
    const float* __restrict__ m1w2, const float* __restrict__ m1b2,
    const float* __restrict__ m2w2, const float* __restrict__ m2b2,
    const float* __restrict__ wsf,
    float* __restrict__ out, int n) {
  __shared__ f32x2 AB[NCELL][THREADS];   // [cell][tid] -> conflict-free dyn read
  int i = blockIdx.x * THREADS + threadIdx.x;
  if (i >= n) return;

  float2 xi = reinterpret_cast<const float2*>(x)[i];
  // xs = x[:, [1,0]]: x1 = x[:,1], x2 = x[:,0]; both clipped first
  float x2v = fminf(fmaxf(xi.x, 1e-7f), 1.0f - 1e-7f);
  float x1v = fminf(fmaxf(xi.y, 1e-7f), 1.0f - 1e-7f);

  f32x2* abcol = &AB[0][threadIdx.x];
  float amin;

  // theta2 = mlp(x1, m2); z2,g2 = flow(x2, theta2)
  mlp_A(x1v, m2w2, m2b2, wsf + 130, abcol, amin);
  bool hl2 = __any(amin < 1e-10f);
  float z2, ld2;
  flow_dev(x2v, abcol, hl2, z2, ld2);

  // theta1 = mlp(z2, m1); z1,g1 = flow(x1, theta1)
  mlp_A(z2, m1w2, m1b2, wsf, abcol, amin);
  bool hl1 = __any(amin < 1e-10f);
  float z1, ld1;
  flow_dev(x1v, abcol, hl1, z1, ld1);

  // z = [z2, z1]; log_dz_dx = [ld2, ld1]
  reinterpret_cast<float2*>(out)[i] = make_float2(z2, z1);
  reinterpret_cast<float2*>(out + 2 * (size_t)n)[i] = make_float2(ld2, ld1);
}

extern "C" void kernel_launch(void* const* d_in, const int* in_sizes, int n_in,
                              void* d_out, int out_size, void* d_ws, size_t ws_size,
                              hipStream_t stream) {
  const float* x    = (const float*)d_in[0];
  const float* m1w0 = (const float*)d_in[1];
  const float* m1b0 = (const float*)d_in[2];
  const float* m1w1 = (const float*)d_in[3];
  const float* m1b1 = (const float*)d_in[4];
  const float* m1w2 = (const float*)d_in[5];
  const float* m1b2 = (const float*)d_in[6];
  const float* m1w3 = (const float*)d_in[7];
  const float* m1b3 = (const float*)d_in[8];
  const float* m2w0 = (const float*)d_in[9];
  const float* m2b0 = (const float*)d_in[10];
  const float* m2w1 = (const float*)d_in[11];
  const float* m2b1 = (const float*)d_in[12];
  const float* m2w2 = (const float*)d_in[13];
  const float* m2b2 = (const float*)d_in[14];
  const float* m2w3 = (const float*)d_in[15];
  const float* m2b3 = (const float*)d_in[16];
  float* out = (float*)d_out;
  float* wsf = (float*)d_ws;
  int n = in_sizes[0] / 2;

  Basis bs;
  compute_basis_host(&bs);

  fold_kernel<<<1, THREADS, 0, stream>>>(
      m1w0, m1b0, m1w1, m1b1, m1w3, m1b3,
      m2w0, m2b0, m2w1, m2b1, m2w3, m2b3, wsf, bs);

  dim3 grid((n + THREADS - 1) / THREADS), block(THREADS);
  cpab2d_kernel<<<grid, block, 0, stream>>>(
      x, m1w2, m1b2, m2w2, m2b2, wsf, out, n);
}

// Round 18
// 45.662 us; speedup vs baseline: 1.0101x; 1.0101x over previous
//
#include <hip/hip_runtime.h>
#include <cmath>

#define THREADS 256
#define NCELL 10
#define DDIM 9

#define LN2F 0.69314718056f
#define RLN2F 1.4426950408889634f  /* 1/ln2 */
#define K10L 14.426950408889634f   /* 10/ln2 */
#define LIN_THR_L 1.442695e-10f    /* 1e-10/ln2 */

typedef float f32x2 __attribute__((ext_vector_type(2)));
typedef float f32x4 __attribute__((ext_vector_type(4)));

__device__ __forceinline__ f32x2 fma2(f32x2 a, f32x2 b, f32x2 c) {
  return __builtin_elementwise_fma(a, b, c);   // v_pk_fma_f32 on gfx950
}
__device__ __forceinline__ f32x2 max2(f32x2 a, f32x2 b) {
  return __builtin_elementwise_max(a, b);      // v_pk_max_f32
}

struct Basis { float Bt[DDIM][2 * NCELL]; }; // Bt[t][l] = B[l][t]

// Reproduce numpy.linalg.svd(L) Vt[11:] rows: LAPACK dgesdd Path 4t leaves
// rows m..n-1 of VT equal to the LQ-factorization orthogonal complement.
static void compute_basis_host(Basis* bs) {
  double L[11][20];
  for (int r = 0; r < 11; ++r)
    for (int c = 0; c < 20; ++c) L[r][c] = 0.0;
  for (int k = 1; k < NCELL; ++k) {
    double xk = (double)k / (double)NCELL;
    L[k - 1][2 * (k - 1)] = xk;
    L[k - 1][2 * (k - 1) + 1] = 1.0;
    L[k - 1][2 * k] = -xk;
    L[k - 1][2 * k + 1] = -1.0;
  }
  L[NCELL - 1][1] = 1.0;
  L[NCELL][2 * (NCELL - 1)] = 1.0;
  L[NCELL][2 * (NCELL - 1) + 1] = 1.0;

  double v[11][20];
  double tau[11];
  for (int i = 0; i < 11; ++i) {
    double alpha = L[i][i];
    double xn2 = 0.0;
    for (int l = i + 1; l < 20; ++l) xn2 += L[i][l] * L[i][l];
    double xnorm = sqrt(xn2);
    for (int l = 0; l < 20; ++l) v[i][l] = 0.0;
    v[i][i] = 1.0;
    if (xnorm == 0.0) {
      tau[i] = 0.0;
    } else {
      double beta = sqrt(alpha * alpha + xn2);
      if (alpha >= 0.0) beta = -beta;        // dlarfg: beta = -sign(alpha)*norm
      tau[i] = (beta - alpha) / beta;
      double sc = 1.0 / (alpha - beta);
      for (int l = i + 1; l < 20; ++l) v[i][l] = L[i][l] * sc;
      L[i][i] = beta;
      for (int j = i + 1; j < 11; ++j) {
        double w = 0.0;
        for (int l = i; l < 20; ++l) w += L[j][l] * v[i][l];
        w *= tau[i];
        for (int l = i; l < 20; ++l) L[j][l] -= w * v[i][l];
      }
    }
  }
  for (int j = 11; j < 20; ++j) {
    double q[20];
    for (int l = 0; l < 20; ++l) q[l] = 0.0;
    q[j] = 1.0;
    for (int i = 10; i >= 0; --i) {
      double w = 0.0;
      for (int l = i; l < 20; ++l) w += v[i][l] * q[l];
      w *= tau[i];
      for (int l = i; l < 20; ++l) q[l] -= w * v[i][l];
    }
    for (int l = 0; l < 20; ++l) bs->Bt[j - 11][l] = (float)q[l];
  }
}

// Per-MLP folds (130 floats each; m1 at ws[0], m2 at ws[130]):
//  [0:10)    W01[j]  = sum_r w0[r]*w1[r,j]       (layer0+1 fold: NO ReLU between)
//  [10:20)   B01[j]  = sum_r b0[r]*w1[r,j] + b1[j]
//  [20:120)  W3V[r][k] = sum_t w3[r,t]*VB[t][k+1], k=0..8; k=9 -> 0 (v10 pad)
//  [120:130) B3V[k]  = sum_t b3[t]*VB[t][k+1],  k=0..8; k=9 -> 0
__global__ void fold_kernel(
    const float* __restrict__ w0_1, const float* __restrict__ b0_1,
    const float* __restrict__ w1_1, const float* __restrict__ b1_1,
    const float* __restrict__ w3_1, const float* __restrict__ b3_1,
    const float* __restrict__ w0_2, const float* __restrict__ b0_2,
    const float* __restrict__ w1_2, const float* __restrict__ b1_2,
    const float* __restrict__ w3_2, const float* __restrict__ b3_2,
    float* __restrict__ ws, Basis bb) {
  for (int f = threadIdx.x; f < 260; f += THREADS) {
    int m = f / 130;
    int j = f % 130;
    const float* w0 = (m == 0) ? w0_1 : w0_2;
    const float* b0 = (m == 0) ? b0_1 : b0_2;
    const float* w1 = (m == 0) ? w1_1 : w1_2;
    const float* w3 = (m == 0) ? w3_1 : w3_2;
    const float* b3 = (m == 0) ? b3_1 : b3_2;
    const float* b1 = (m == 0) ? b1_1 : b1_2;
    float val = 0.0f;
    if (j < 10) {
      for (int r = 0; r < 10; ++r) val += w0[r] * w1[r * 10 + j];
    } else if (j < 20) {
      int jj = j - 10;
      for (int r = 0; r < 10; ++r) val += b0[r] * w1[r * 10 + jj];
      val += b1[jj];
    } else if (j < 120) {
      int jj = j - 20;
      int r = jj / 10, k = jj % 10;
      if (k < 9) {
        float g = (float)(k + 1) * 0.1f;
        for (int t = 0; t < DDIM; ++t)
          val += w3[r * DDIM + t] * (bb.Bt[t][2 * (k + 1)] * g + bb.Bt[t][2 * (k + 1) + 1]);
      }
    } else {
      int k = j - 120;
      if (k < 9) {
        float g = (float)(k + 1) * 0.1f;
        for (int t = 0; t < DDIM; ++t)
          val += b3[t] * (bb.Bt[t][2 * (k + 1)] * g + bb.Bt[t][2 * (k + 1) + 1]);
      }
    }
    ws[f] = val;
  }
}

// Folded MLP: h1 = relu(x*W01+B01); h2 = relu(h1@w2+b2); v1..v9 = h2@W3V+B3V
// (v0 = v10 = 0). Derive per cell: a_c = 10*(v[c+1]-v[c]),
// b_c = v[c] - a_c*(c/10) — identical to theta@B^T in exact arithmetic.
// Writes (a,b) to this thread's LDS column; returns min|a| for the lin vote.
__device__ __forceinline__ void mlp_A(float xin,
    const float* __restrict__ w2, const float* __restrict__ b2,
    const float* __restrict__ wbf,     // 130 floats (layout above)
    f32x2* abcol, float& amin) {
  const f32x2* W01 = (const f32x2*)wbf;         // [0:5)
  const f32x2* B01 = W01 + 5;                   // [5:10)
  const f32x2* W3V = W01 + 10;                  // [10:60): 10 rows x 5 pairs
  const f32x2* B3V = W01 + 60;                  // [60:65)
  const f32x2* w2p = (const f32x2*)w2;
  const f32x2* b2p = (const f32x2*)b2;

  f32x2 h1[5], h2[5];
  f32x2 xx = {xin, xin};
  f32x2 zero = {0.0f, 0.0f};
#pragma unroll
  for (int p = 0; p < 5; ++p) h1[p] = max2(fma2(xx, W01[p], B01[p]), zero);

#pragma unroll
  for (int p = 0; p < 5; ++p) h2[p] = b2p[p];
#pragma unroll
  for (int r = 0; r < 10; ++r) {
    float h = h1[r >> 1][r & 1];
    f32x2 hh = {h, h};
#pragma unroll
    for (int p = 0; p < 5; ++p) h2[p] = fma2(hh, w2p[r * 5 + p], h2[p]);
  }
#pragma unroll
  for (int p = 0; p < 5; ++p) h2[p] = max2(h2[p], zero);

  f32x2 vp[5];                                   // (v1,v2)..(v9,v10=0)
#pragma unroll
  for (int p = 0; p < 5; ++p) vp[p] = B3V[p];
#pragma unroll
  for (int r = 0; r < 10; ++r) {
    float h = h2[r >> 1][r & 1];
    f32x2 hh = {h, h};
#pragma unroll
    for (int p = 0; p < 5; ++p) vp[p] = fma2(hh, W3V[r * 5 + p], vp[p]);
  }

  float v[NCELL + 1];
  v[0] = 0.0f;
#pragma unroll
  for (int k = 1; k <= NCELL; ++k) v[k] = vp[(k - 1) >> 1][(k - 1) & 1];

  float mn = 1e30f;
#pragma unroll
  for (int c = 0; c < NCELL; ++c) {
    float ac = (v[c + 1] - v[c]) * 10.0f;
    float bc = fmaf(ac, -(float)c * 0.1f, v[c]);
    f32x2 ab; ab[0] = ac; ab[1] = bc;
    abcol[c * THREADS] = ab;
    mn = fminf(mn, fabsf(ac));
  }
  amin = mn;
}

// Freeze-form cell-hop loop (best-measured r13 structure):
//  - v continuous across cells -> v_entry := vxc_prev register-exact; no
//    per-iter v=fma(a,phi,b).
//  - monotone direction -> dir/d01 hoisted; xc += d01; c += dirI.
//  - terminal lanes are fixed points of the update (cross=false sticks);
//    no active/trem bookkeeping. Exit vote __all(!cross).
//  - exp/evolve deferred post-loop; ld telescoped to terminal ENTRY:
//    ld = log(vterm/v0) + aF*t with the evolve factor added in LOG SPACE
//    (exact) — never recompute v(z) (r12 cancellation lesson).
//  - guards: ratio clamp 1e-30, |v|<1e-14 tiny -> no-cross, lin fixup
//    behind wave-uniform __any(lin) vote (hoisted from mlp_A's min|a|).
__device__ __forceinline__ void flow_dev(float x0, const f32x2* abcol,
                                         bool has_lin, float& zo, float& ldo) {
  int c = (int)(x0 * 10.0f);
  c = c < 0 ? 0 : (c > 9 ? 9 : c);
  f32x2 ab = abcol[c * THREADS];
  float a = ab[0], b = ab[1];
  float v0 = fmaf(a, x0, b);
  bool right = (v0 >= 0.0f);
  float d01 = right ? 0.1f : -0.1f;
  int dirI = right ? 1 : -1;
  float xc = (float)(right ? (c + 1) : c) * 0.1f;
  float rv0 = __builtin_amdgcn_rcpf(v0);
  float rv = rv0;
  bool tiny = fabsf(v0) < 1e-14f;
  float ra = __builtin_amdgcn_rcpf(a);
  float phiC = x0;           // entry point of current cell
  float t = 1.0f;            // remaining time; freezes at terminal
  bool cross = false;

  // prefetch next cell in travel direction
  int cn = c + dirI; cn = cn < 0 ? 0 : (cn > 9 ? 9 : cn);
  f32x2 abn = abcol[cn * THREADS];
  float ran = __builtin_amdgcn_rcpf(abn[0]);

  for (int it = 0; it < NCELL; ++it) {
    float vxc = fmaf(a, xc, b);
    float ratio = fmaxf(vxc * rv, 1e-30f);
    float l = __logf(ratio);                       // v_log_f32
    float thit = l * ra;
    if (has_lin) {                                 // hoisted; ~never taken
      bool lin = fabsf(a) < 1e-10f;
      float sb = (fabsf(b) < 1e-30f) ? 1.0f : b;
      float tl = (xc - phiC) * __builtin_amdgcn_rcpf(sb);
      thit = lin ? tl : thit;
    }
    cross = (thit < t) && !tiny;
    t = cross ? (t - thit) : t;
    phiC = cross ? xc : phiC;
    float rvn = __builtin_amdgcn_rcpf(vxc);        // off-chain
    rv = cross ? rvn : rv;
    tiny = cross ? (fabsf(vxc) < 1e-14f) : tiny;
    a = cross ? abn[0] : a;
    b = cross ? abn[1] : b;
    ra = cross ? ran : ra;
    xc = cross ? (xc + d01) : xc;
    c = cross ? cn : c;
    if (__all(!cross)) break;
    int cnn = c + dirI; cnn = cnn < 0 ? 0 : (cnn > 9 ? 9 : cnn);
    abn = abcol[cnn * THREADS];                    // prefetch for next iter
    ran = __builtin_amdgcn_rcpf(abn[0]);
    cn = cnn;
  }
  // post-loop: telescoped ld (v_term/v0) + one evolve inside the terminal
  // cell (reference formulas); (a,b)/phiC/t all live in registers.
  bool done = !cross;        // false only if still crossing at exhaustion
  float vterm = fmaf(a, phiC, b);
  float ld = __logf(fmaxf(vterm * rv0, 1e-30f));   // == sum of crossed log-ratios
  bool linf = fabsf(a) < 1e-10f;
  float rsaf = __builtin_amdgcn_rcpf(linf ? 1.0f : a);
  float bsa = b * rsaf;
  float E = __expf(a * t);                         // the ONLY exp in the flow
  float pnl = fmaf(phiC + bsa, E, -bsa);
  float pli = fmaf(b, t, phiC);
  float p1 = linf ? pli : pnl;
  zo = done ? p1 : phiC;
  ldo = ld + (done ? a * t : 0.0f);
}

__global__ __launch_bounds__(THREADS, 4) void cpab2d_kernel(
    const float* __restrict__ x,
    const float* __restrict__ m1w2, const float* __restrict__ m1b2,
    const float* __restrict__ m2w2, const float* __restrict__ m2b2,
    const float* __restrict__ wsf,
    float* __restrict__ out, int n) {
  __shared__ f32x2 AB[NCELL][THREADS];   // [cell][tid] -> conflict-free dyn read
  int i = blockIdx.x * THREADS + threadIdx.x;
  if (i >= n) return;

  float2 xi = reinterpret_cast<const float2*>(x)[i];
  // xs = x[:, [1,0]]: x1 = x[:,1], x2 = x[:,0]; both clipped first
  float x2v = fminf(fmaxf(xi.x, 1e-7f), 1.0f - 1e-7f);
  float x1v = fminf(fmaxf(xi.y, 1e-7f), 1.0f - 1e-7f);

  f32x2* abcol = &AB[0][threadIdx.x];
  float amin;

  // theta2 = mlp(x1, m2); z2,g2 = flow(x2, theta2)
  mlp_A(x1v, m2w2, m2b2, wsf + 130, abcol, amin);
  bool hl2 = __any(amin < 1e-10f);
  float z2, ld2;
  flow_dev(x2v, abcol, hl2, z2, ld2);

  // theta1 = mlp(z2, m1); z1,g1 = flow(x1, theta1)
  mlp_A(z2, m1w2, m1b2, wsf, abcol, amin);
  bool hl1 = __any(amin < 1e-10f);
  float z1, ld1;
  flow_dev(x1v, abcol, hl1, z1, ld1);

  // z = [z2, z1]; log_dz_dx = [ld2, ld1]
  reinterpret_cast<float2*>(out)[i] = make_float2(z2, z1);
  reinterpret_cast<float2*>(out + 2 * (size_t)n)[i] = make_float2(ld2, ld1);
}

extern "C" void kernel_launch(void* const* d_in, const int* in_sizes, int n_in,
                              void* d_out, int out_size, void* d_ws, size_t ws_size,
                              hipStream_t stream) {
  const float* x    = (const float*)d_in[0];
  const float* m1w0 = (const float*)d_in[1];
  const float* m1b0 = (const float*)d_in[2];
  const float* m1w1 = (const float*)d_in[3];
  const float* m1b1 = (const float*)d_in[4];
  const float* m1w2 = (const float*)d_in[5];
  const float* m1b2 = (const float*)d_in[6];
  const float* m1w3 = (const float*)d_in[7];
  const float* m1b3 = (const float*)d_in[8];
  const float* m2w0 = (const float*)d_in[9];
  const float* m2b0 = (const float*)d_in[10];
  const float* m2w1 = (const float*)d_in[11];
  const float* m2b1 = (const float*)d_in[12];
  const float* m2w2 = (const float*)d_in[13];
  const float* m2b2 = (const float*)d_in[14];
  const float* m2w3 = (const float*)d_in[15];
  const float* m2b3 = (const float*)d_in[16];
  float* out = (float*)d_out;
  float* wsf = (float*)d_ws;
  int n = in_sizes[0] / 2;

  Basis bs;
  compute_basis_host(&bs);

  fold_kernel<<<1, THREADS, 0, stream>>>(
      m1w0, m1b0, m1w1, m1b1, m1w3, m1b3,
      m2w0, m2b0, m2w1, m2b1, m2w3, m2b3, wsf, bs);

  dim3 grid((n + THREADS - 1) / THREADS), block(THREADS);
  cpab2d_kernel<<<grid, block, 0, stream>>>(
      x, m1w2, m1b2, m2w2, m2b2, wsf, out, n);
}